// Round 5
// baseline (167.946 us; speedup 1.0000x reference)
//
#include <hip/hip_runtime.h>
#include <math.h>

// Problem constants
#define CC   128         // channels
#define NL   16384       // N * H * W = 4*64*64
#define OMP  112         // padded om row stride (108 real cols)
#define HH   64
#define WW   64

typedef __attribute__((ext_vector_type(8))) short short8;
typedef __attribute__((ext_vector_type(4))) float f32x4;

__device__ __forceinline__ unsigned short f2bf(float f) {
    union { float f; unsigned u; } v; v.f = f;
    unsigned r = v.u + 0x7fff + ((v.u >> 16) & 1);   // RNE
    return (unsigned short)(r >> 16);
}
__device__ __forceinline__ float bf2f(unsigned short u) {
    union { unsigned u; float f; } v; v.u = ((unsigned)u) << 16;
    return v.f;
}

// ---------------------------------------------------------------------------
// Weight prep + stats zero.
// Wcomb[256][128] bf16: rows 0..127 = Wv^T, 128..239 = Wom^T (pad), 240..255 = 0
// WoT[128][128] = Wo^T ; Wcb[128][128] = Wc ([o][c] is already Bt layout).
// stats: 2 stages x 8 groups x 256 floats = 4096 floats, zeroed.
// ---------------------------------------------------------------------------
__global__ __launch_bounds__(256) void prep_kernel(
    const float* __restrict__ Wv, const float* __restrict__ Wom,
    const float* __restrict__ Wo, const float* __restrict__ Wc,
    unsigned short* __restrict__ Wcomb, unsigned short* __restrict__ WoT,
    unsigned short* __restrict__ Wcb, float* __restrict__ stats)
{
    int tid = threadIdx.x;
    int b   = blockIdx.x;
    if (b < 16) stats[b * 256 + tid] = 0.0f;
    int i = b * 256 + tid;                      // 65536 total
    if (i < 32768) {
        int r = i >> 7, k = i & 127;
        unsigned short v;
        if (r < 128)      v = f2bf(Wv[k * CC + r]);
        else if (r < 240) { int nn = r - 128; v = (nn < 108) ? f2bf(Wom[k * 108 + nn]) : (unsigned short)0; }
        else              v = 0;
        Wcomb[i] = v;
    } else if (i < 49152) {
        int j = i - 32768; int nn = j >> 7, k = j & 127;
        WoT[j] = f2bf(Wo[k * CC + nn]);
    } else {
        int j = i - 49152;
        Wcb[j] = f2bf(Wc[j]);
    }
}

// ---------------------------------------------------------------------------
// Fused value+om GEMM: [M=16384 x N=240(256 pad) x K=128].
// 16-row tile per block (grid 1024 -> 4 blocks/CU), 4 waves split N:
// wave w handles n-tiles {w, w+4, w+8, w+12}. B frags straight from L2.
// IN_MODE 0: A = x NCHW (LDS transpose). IN_MODE 1: A = bn_relu(ybuf) NHWC.
// ---------------------------------------------------------------------------
template<int IN_MODE>
__global__ __launch_bounds__(256) void gemm_vom_kernel(
    const float* __restrict__ Ain, const unsigned short* __restrict__ Wcomb,
    const float* __restrict__ bv, const float* __restrict__ bom,
    const float* __restrict__ stats, const float* __restrict__ gamma,
    const float* __restrict__ beta,
    unsigned short* __restrict__ val, float* __restrict__ omb)
{
    __shared__ unsigned short As[16 * 136];
    __shared__ float bnsc[128], bnsh[128];

    int tid = threadIdx.x;
    int block_m = blockIdx.x * 16;

    if (IN_MODE == 1) {
        if (tid < 128) {
            float s = 0.0f, sq = 0.0f;
#pragma unroll
            for (int g = 0; g < 8; g++) {
                s  += stats[g * 256 + tid];
                sq += stats[g * 256 + 128 + tid];
            }
            const float inv = 1.0f / 16384.0f;
            float mean = s * inv;
            float var  = sq * inv - mean * mean;
            float sc   = rsqrtf(var + 1e-5f) * gamma[tid];
            bnsc[tid] = sc;
            bnsh[tid] = beta[tid] - mean * sc;
        }
        __syncthreads();
    }

    if (IN_MODE == 0) {
        int n   = block_m >> 12;
        int hw0 = block_m & 4095;
#pragma unroll
        for (int i = 0; i < 2; i++) {
            int id = tid + i * 256;              // 0..511
            int c  = id >> 2, j4 = id & 3;
            float4 v = *(const float4*)(Ain + (((size_t)(n * CC + c)) << 12) + hw0 + j4 * 4);
            As[(j4 * 4 + 0) * 136 + c] = f2bf(v.x);
            As[(j4 * 4 + 1) * 136 + c] = f2bf(v.y);
            As[(j4 * 4 + 2) * 136 + c] = f2bf(v.z);
            As[(j4 * 4 + 3) * 136 + c] = f2bf(v.w);
        }
    } else {
#pragma unroll
        for (int i = 0; i < 2; i++) {
            int id = tid + i * 256;
            int r  = id >> 5, c = (id & 31) * 4;
            float4 v = *(const float4*)(Ain + (size_t)(block_m + r) * CC + c);
            As[r * 136 + c + 0] = f2bf(fmaxf(v.x * bnsc[c + 0] + bnsh[c + 0], 0.0f));
            As[r * 136 + c + 1] = f2bf(fmaxf(v.y * bnsc[c + 1] + bnsh[c + 1], 0.0f));
            As[r * 136 + c + 2] = f2bf(fmaxf(v.z * bnsc[c + 2] + bnsh[c + 2], 0.0f));
            As[r * 136 + c + 3] = f2bf(fmaxf(v.w * bnsc[c + 3] + bnsh[c + 3], 0.0f));
        }
    }
    __syncthreads();

    int w  = tid >> 6;
    int l  = tid & 63;
    int lr = l & 15, lk = l >> 4;

    f32x4 acc[4];
#pragma unroll
    for (int nt = 0; nt < 4; nt++) acc[nt] = (f32x4){0.f, 0.f, 0.f, 0.f};

#pragma unroll
    for (int kk = 0; kk < 4; kk++) {
        short8 a = *(const short8*)(&As[lr * 136 + kk * 32 + lk * 8]);
#pragma unroll
        for (int nt = 0; nt < 4; nt++) {
            int ntile = w + nt * 4;
            short8 b = *(const short8*)(Wcomb + (size_t)(ntile * 16 + lr) * CC + kk * 32 + lk * 8);
            acc[nt] = __builtin_amdgcn_mfma_f32_16x16x32_bf16(a, b, acc[nt], 0, 0, 0);
        }
    }

    int row0 = block_m + lk * 4;
#pragma unroll
    for (int nt = 0; nt < 4; nt++) {
        int col = (w + nt * 4) * 16 + lr;        // 0..255
        if (col < 128) {
            float bb = bv[col];
#pragma unroll
            for (int r = 0; r < 4; r++)
                val[(size_t)(row0 + r) * CC + col] = f2bf(acc[nt][r] + bb);
        } else if (col < 240) {
            int oc = col - 128;                  // 0..111
            float bb = (oc < 108) ? bom[oc] : 0.0f;
#pragma unroll
            for (int r = 0; r < 4; r++)
                omb[(size_t)(row0 + r) * OMP + oc] = acc[nt][r] + bb;
        }
    }
}

// ---------------------------------------------------------------------------
// Deformable sampling (bf16 value): 16 lanes per (nl,g) unit, 2 channels/lane.
// ---------------------------------------------------------------------------
__global__ __launch_bounds__(256) void sample_kernel(
    const unsigned short* __restrict__ val, const float* __restrict__ omb,
    unsigned int* __restrict__ sbuf)
{
    int tid    = threadIdx.x;
    int gid    = blockIdx.x * 256 + tid;
    int unit   = gid >> 4;                   // 65536 units
    int lane16 = gid & 15;
    int nl = unit >> 2;
    int g  = unit & 3;
    int n  = nl >> 12;
    int hw = nl & 4095;
    int h  = hw >> 6;
    int w  = hw & 63;

    const float* omp = omb + (size_t)nl * OMP + g * 27;
    const unsigned short* vb = val + (((size_t)n) << 19) + g * 32 + lane16 * 2;

    float acc0 = 0.0f, acc1 = 0.0f;
#pragma unroll
    for (int k = 0; k < 9; k++) {
        float ox = omp[2 * k];
        float oy = omp[2 * k + 1];
        float mk = omp[18 + k];
        float ly = (float)(h + k / 3 - 1) + oy;
        float lx = (float)(w + k % 3 - 1) + ox;
        float y0f = floorf(ly), x0f = floorf(lx);
        float wy = ly - y0f, wx = lx - x0f;
        int y0 = (int)y0f, x0 = (int)x0f;

        float v0 = 0.0f, v1 = 0.0f;
#pragma unroll
        for (int cy = 0; cy < 2; cy++) {
#pragma unroll
            for (int cx = 0; cx < 2; cx++) {
                int yi = y0 + cy, xi = x0 + cx;
                float wgt = (cy ? wy : 1.0f - wy) * (cx ? wx : 1.0f - wx);
                bool valid = (yi >= 0) && (yi < HH) && (xi >= 0) && (xi < WW);
                wgt = valid ? wgt : 0.0f;
                int yc = min(max(yi, 0), HH - 1);
                int xc = min(max(xi, 0), WW - 1);
                unsigned int pv = *(const unsigned int*)(vb + (size_t)(yc * WW + xc) * CC);
                v0 += bf2f((unsigned short)(pv & 0xffff)) * wgt;
                v1 += bf2f((unsigned short)(pv >> 16)) * wgt;
            }
        }
        acc0 += mk * v0;
        acc1 += mk * v1;
    }
    unsigned int packed = (unsigned int)f2bf(acc0) | ((unsigned int)f2bf(acc1) << 16);
    sbuf[(size_t)nl * 64 + g * 16 + lane16] = packed;
}

// ---------------------------------------------------------------------------
// Wo GEMM + fused BN-stats. Zero staging LDS: A & B frags direct from global.
// 16-row tile (grid 1024), wave w covers cols w*32..w*32+31 (2 n-tiles).
// Stats go to 8 slot groups to cap atomic contention.
// ---------------------------------------------------------------------------
__global__ __launch_bounds__(256) void gemm_o_bn_kernel(
    const unsigned short* __restrict__ A, const unsigned short* __restrict__ Bt,
    float* __restrict__ ybuf, float* __restrict__ stats)
{
    __shared__ float lstat[256];
    int tid = threadIdx.x;
    int block_m = blockIdx.x * 16;
    lstat[tid] = 0.0f;
    __syncthreads();

    int w  = tid >> 6;
    int l  = tid & 63;
    int lr = l & 15, lk = l >> 4;

    f32x4 acc[2];
    acc[0] = (f32x4){0.f, 0.f, 0.f, 0.f};
    acc[1] = (f32x4){0.f, 0.f, 0.f, 0.f};

#pragma unroll
    for (int kk = 0; kk < 4; kk++) {
        short8 a = *(const short8*)(A + (size_t)(block_m + lr) * CC + kk * 32 + lk * 8);
#pragma unroll
        for (int nt = 0; nt < 2; nt++) {
            short8 b = *(const short8*)(Bt + (size_t)((w * 2 + nt) * 16 + lr) * CC + kk * 32 + lk * 8);
            acc[nt] = __builtin_amdgcn_mfma_f32_16x16x32_bf16(a, b, acc[nt], 0, 0, 0);
        }
    }

    int row0 = block_m + lk * 4;
#pragma unroll
    for (int nt = 0; nt < 2; nt++) {
        int col = (w * 2 + nt) * 16 + lr;
        float s = 0.0f, sq = 0.0f;
#pragma unroll
        for (int r = 0; r < 4; r++) {
            float v = acc[nt][r];
            ybuf[(size_t)(row0 + r) * CC + col] = v;
            s += v;
            sq += v * v;
        }
        atomicAdd(&lstat[col], s);
        atomicAdd(&lstat[128 + col], sq);
    }
    __syncthreads();
    if (tid < 128) {
        float* sg = stats + (blockIdx.x & 7) * 256;
        atomicAdd(&sg[tid], lstat[tid]);
        atomicAdd(&sg[128 + tid], lstat[128 + tid]);
    }
}

// ---------------------------------------------------------------------------
// Final GEMM: A = bn(ybuf) + x_residual(NCHW), B = Wc; out NCHW fp32.
// 16-row tile (grid 1024), wave w covers 2 n-tiles. B frags direct.
// ---------------------------------------------------------------------------
__global__ __launch_bounds__(256) void gemm_final_kernel(
    const float* __restrict__ ybuf, const float* __restrict__ x,
    const unsigned short* __restrict__ Bt, const float* __restrict__ stats,
    const float* __restrict__ gamma, const float* __restrict__ beta,
    float* __restrict__ out)
{
    __shared__ unsigned short As[16 * 136];
    __shared__ float Xs[16 * 132];
    __shared__ float T[128 * 20];
    __shared__ float bnsc[128], bnsh[128];

    int tid = threadIdx.x;
    int block_m = blockIdx.x * 16;
    int n   = block_m >> 12;
    int hw0 = block_m & 4095;

    if (tid < 128) {
        float s = 0.0f, sq = 0.0f;
#pragma unroll
        for (int g = 0; g < 8; g++) {
            s  += stats[g * 256 + tid];
            sq += stats[g * 256 + 128 + tid];
        }
        const float inv = 1.0f / 16384.0f;
        float mean = s * inv;
        float var  = sq * inv - mean * mean;
        float sc   = rsqrtf(var + 1e-5f) * gamma[tid];
        bnsc[tid] = sc;
        bnsh[tid] = beta[tid] - mean * sc;
    }

    // stage x residual (NCHW -> LDS transpose, fp32)
#pragma unroll
    for (int i = 0; i < 2; i++) {
        int id = tid + i * 256;
        int c  = id >> 2, j4 = id & 3;
        float4 v = *(const float4*)(x + (((size_t)(n * CC + c)) << 12) + hw0 + j4 * 4);
        Xs[(j4 * 4 + 0) * 132 + c] = v.x;
        Xs[(j4 * 4 + 1) * 132 + c] = v.y;
        Xs[(j4 * 4 + 2) * 132 + c] = v.z;
        Xs[(j4 * 4 + 3) * 132 + c] = v.w;
    }
    __syncthreads();

    // stage A = bn(ybuf) + Xs
#pragma unroll
    for (int i = 0; i < 2; i++) {
        int id = tid + i * 256;
        int r  = id >> 5, c = (id & 31) * 4;
        float4 v = *(const float4*)(ybuf + (size_t)(block_m + r) * CC + c);
        As[r * 136 + c + 0] = f2bf(v.x * bnsc[c + 0] + bnsh[c + 0] + Xs[r * 132 + c + 0]);
        As[r * 136 + c + 1] = f2bf(v.y * bnsc[c + 1] + bnsh[c + 1] + Xs[r * 132 + c + 1]);
        As[r * 136 + c + 2] = f2bf(v.z * bnsc[c + 2] + bnsh[c + 2] + Xs[r * 132 + c + 2]);
        As[r * 136 + c + 3] = f2bf(v.w * bnsc[c + 3] + bnsh[c + 3] + Xs[r * 132 + c + 3]);
    }
    __syncthreads();

    int w  = tid >> 6;
    int l  = tid & 63;
    int lr = l & 15, lk = l >> 4;

    f32x4 acc[2];
    acc[0] = (f32x4){0.f, 0.f, 0.f, 0.f};
    acc[1] = (f32x4){0.f, 0.f, 0.f, 0.f};

#pragma unroll
    for (int kk = 0; kk < 4; kk++) {
        short8 a = *(const short8*)(&As[lr * 136 + kk * 32 + lk * 8]);
#pragma unroll
        for (int nt = 0; nt < 2; nt++) {
            short8 b = *(const short8*)(Bt + (size_t)((w * 2 + nt) * 16 + lr) * CC + kk * 32 + lk * 8);
            acc[nt] = __builtin_amdgcn_mfma_f32_16x16x32_bf16(a, b, acc[nt], 0, 0, 0);
        }
    }

    // NCHW scatter via LDS transpose
#pragma unroll
    for (int nt = 0; nt < 2; nt++) {
        int col = (w * 2 + nt) * 16 + lr;
#pragma unroll
        for (int r = 0; r < 4; r++)
            T[col * 20 + lk * 4 + r] = acc[nt][r];
    }
    __syncthreads();
#pragma unroll
    for (int i = 0; i < 2; i++) {
        int id = tid + i * 256;
        int o  = id >> 2, j4 = id & 3;
        float4 v = *(const float4*)(&T[o * 20 + j4 * 4]);
        *(float4*)(out + (((size_t)(n * CC + o)) << 12) + hw0 + j4 * 4) = v;
    }
}

// ---------------------------------------------------------------------------
extern "C" void kernel_launch(void* const* d_in, const int* in_sizes, int n_in,
                              void* d_out, int out_size, void* d_ws, size_t ws_size,
                              hipStream_t stream)
{
    const float* x     = (const float*)d_in[0];
    const float* Wv    = (const float*)d_in[1];
    const float* bv    = (const float*)d_in[2];
    const float* Wom   = (const float*)d_in[3];
    const float* bom   = (const float*)d_in[4];
    const float* Wo    = (const float*)d_in[5];
    const float* gamma = (const float*)d_in[6];
    const float* beta  = (const float*)d_in[7];
    const float* Wc    = (const float*)d_in[8];
    float* out = (float*)d_out;

    char* ws = (char*)d_ws;
    unsigned short* val   = (unsigned short*)ws;   ws += (size_t)NL * CC * 2;    // 4 MB
    float*          omb   = (float*)ws;            ws += (size_t)NL * OMP * 4;   // 7.34 MB
    unsigned int*   sbuf  = (unsigned int*)ws;     ws += (size_t)NL * CC * 2;    // 4 MB
    float*          ybuf  = (float*)ws;            ws += (size_t)NL * CC * 4;    // 8 MB
    unsigned short* Wcomb = (unsigned short*)ws;   ws += 256 * 128 * 2;
    unsigned short* WoT   = (unsigned short*)ws;   ws += 128 * 128 * 2;
    unsigned short* Wcb   = (unsigned short*)ws;   ws += 128 * 128 * 2;
    float*          stats = (float*)ws;            ws += 4096 * 4;               // 2 stages x 8 groups x 256

    dim3 b256(256);

    prep_kernel<<<256, b256, 0, stream>>>(Wv, Wom, Wo, Wc, Wcomb, WoT, Wcb, stats);

    // ---- DCN block 1 ----
    gemm_vom_kernel<0><<<1024, b256, 0, stream>>>(x, Wcomb, bv, bom,
                                                  nullptr, nullptr, nullptr, val, omb);
    sample_kernel<<<4096, b256, 0, stream>>>(val, omb, sbuf);
    gemm_o_bn_kernel<<<1024, b256, 0, stream>>>((const unsigned short*)sbuf, WoT, ybuf, stats);

    // ---- DCN block 2 (bn+relu fused into A-staging) ----
    gemm_vom_kernel<1><<<1024, b256, 0, stream>>>(ybuf, Wcomb, bv, bom,
                                                  stats, gamma, beta, val, omb);
    sample_kernel<<<4096, b256, 0, stream>>>(val, omb, sbuf);
    gemm_o_bn_kernel<<<1024, b256, 0, stream>>>((const unsigned short*)sbuf, WoT, ybuf, stats + 2048);

    // ---- final: bn2 + residual + 1x1 conv, NCHW out ----
    gemm_final_kernel<<<1024, b256, 0, stream>>>(ybuf, x, Wcb, stats + 2048, gamma, beta, out);
}

// Round 8
// 157.599 us; speedup vs baseline: 1.0657x; 1.0657x over previous
//
#include <hip/hip_runtime.h>
#include <math.h>

#define CC   128
#define NL   16384
#define HH   64
#define WW   64

typedef __attribute__((ext_vector_type(8))) short short8;
typedef __attribute__((ext_vector_type(4))) float f32x4;

__device__ __forceinline__ unsigned short f2bf(float f) {
    union { float f; unsigned u; } v; v.f = f;
    unsigned r = v.u + 0x7fff + ((v.u >> 16) & 1);   // RNE
    return (unsigned short)(r >> 16);
}
__device__ __forceinline__ float bf2f(unsigned short u) {
    union { unsigned u; float f; } v; v.u = ((unsigned)u) << 16;
    return v.f;
}

// ---------------------------------------------------------------------------
// vom: val = A @ Wv + bv (bf16, global), omb = A @ Wom + bom (fp32, global).
// 64-row tile, 256 blocks. Weights converted fp32->bf16 in staging.
// IN_MODE 0: A = x NCHW (LDS transpose); also zeroes stats (blocks 0..15).
// IN_MODE 1: A = bn_relu(ybuf NHWC) via stats_in.
// ---------------------------------------------------------------------------
template<int IN_MODE>
__global__ __launch_bounds__(256) void gemm_vom_kernel(
    const float* __restrict__ Ain, const float* __restrict__ Wv,
    const float* __restrict__ bv, const float* __restrict__ Wom,
    const float* __restrict__ bom, const float* __restrict__ stats_in,
    const float* __restrict__ gamma, const float* __restrict__ beta,
    unsigned short* __restrict__ val, float* __restrict__ omb,
    float* __restrict__ stats_zero)
{
    __shared__ unsigned short As[64 * 136];
    __shared__ unsigned short Bs[128 * 136];
    __shared__ float bnsc[128], bnsh[128];

    const int tid = threadIdx.x;
    const int bid = blockIdx.x;
    const int block_m = bid * 64;

    if (IN_MODE == 0) {
        if (bid < 16) stats_zero[bid * 256 + tid] = 0.0f;   // 4096 floats = both stat sets
    } else {
        if (tid < 128) {
            float s = 0.f, sq = 0.f;
#pragma unroll
            for (int g = 0; g < 8; g++) {
                s  += stats_in[g * 256 + tid];
                sq += stats_in[g * 256 + 128 + tid];
            }
            const float inv = 1.0f / 16384.0f;
            float mean = s * inv;
            float var  = sq * inv - mean * mean;
            float sc   = rsqrtf(var + 1e-5f) * gamma[tid];
            bnsc[tid] = sc;
            bnsh[tid] = beta[tid] - mean * sc;
        }
        __syncthreads();
    }

    // ---- stage A ----
    if (IN_MODE == 0) {
        int n_img = block_m >> 12;
        int hw0   = block_m & 4095;
#pragma unroll
        for (int i = 0; i < 8; i++) {
            int id = tid + i * 256;              // 2048 float4
            int c = id >> 4, j4 = id & 15;
            float4 v = *(const float4*)(Ain + (((size_t)(n_img * CC + c)) << 12) + hw0 + j4 * 4);
            As[(j4 * 4 + 0) * 136 + c] = f2bf(v.x);
            As[(j4 * 4 + 1) * 136 + c] = f2bf(v.y);
            As[(j4 * 4 + 2) * 136 + c] = f2bf(v.z);
            As[(j4 * 4 + 3) * 136 + c] = f2bf(v.w);
        }
    } else {
#pragma unroll
        for (int i = 0; i < 8; i++) {
            int id = tid + i * 256;
            int r = id >> 5, c = (id & 31) * 4;
            float4 v = *(const float4*)(Ain + (size_t)(block_m + r) * CC + c);
            As[r * 136 + c + 0] = f2bf(fmaxf(v.x * bnsc[c + 0] + bnsh[c + 0], 0.f));
            As[r * 136 + c + 1] = f2bf(fmaxf(v.y * bnsc[c + 1] + bnsh[c + 1], 0.f));
            As[r * 136 + c + 2] = f2bf(fmaxf(v.z * bnsc[c + 2] + bnsh[c + 2], 0.f));
            As[r * 136 + c + 3] = f2bf(fmaxf(v.w * bnsc[c + 3] + bnsh[c + 3], 0.f));
        }
    }
    // ---- Bs <- Wv^T (transpose-convert) ----
#pragma unroll
    for (int i = 0; i < 16; i++) {
        int id = tid + i * 256;                  // 4096 float4
        int k = id >> 5, n4 = (id & 31) * 4;
        float4 v = *(const float4*)(Wv + (size_t)k * CC + n4);
        Bs[(n4 + 0) * 136 + k] = f2bf(v.x);
        Bs[(n4 + 1) * 136 + k] = f2bf(v.y);
        Bs[(n4 + 2) * 136 + k] = f2bf(v.z);
        Bs[(n4 + 3) * 136 + k] = f2bf(v.w);
    }
    __syncthreads();

    const int w  = tid >> 6;
    const int l  = tid & 63;
    const int lr = l & 15;
    const int lk = l >> 4;

    // ---- val = A @ Wv + bv ----
    {
        f32x4 acc[8];
#pragma unroll
        for (int j = 0; j < 8; j++) acc[j] = (f32x4){0.f, 0.f, 0.f, 0.f};
#pragma unroll
        for (int kk = 0; kk < 4; kk++) {
            short8 a = *(const short8*)(&As[(w * 16 + lr) * 136 + kk * 32 + lk * 8]);
#pragma unroll
            for (int j = 0; j < 8; j++) {
                short8 b = *(const short8*)(&Bs[(j * 16 + lr) * 136 + kk * 32 + lk * 8]);
                acc[j] = __builtin_amdgcn_mfma_f32_16x16x32_bf16(a, b, acc[j], 0, 0, 0);
            }
        }
        int row0 = block_m + w * 16 + lk * 4;
#pragma unroll
        for (int j = 0; j < 8; j++) {
            int col = j * 16 + lr;
            float bb = bv[col];
#pragma unroll
            for (int r = 0; r < 4; r++)
                val[(size_t)(row0 + r) * CC + col] = f2bf(acc[j][r] + bb);
        }
    }
    __syncthreads();

    // ---- Bs <- Wom^T (rows 0..107), rows 108..111 zeroed ----
    if (tid < 68) {
        int r = 108 + tid / 17, q = tid % 17;
        float4 z; z.x = 0.f; z.y = 0.f; z.z = 0.f; z.w = 0.f;
        *(float4*)(&Bs[r * 136 + q * 8]) = z;
    }
#pragma unroll
    for (int i = 0; i < 14; i++) {
        int id = tid + i * 256;                  // 3456 float4 of Wom[128][108]
        if (id < 3456) {
            int k = id / 27, q = id - k * 27;
            float4 v = *(const float4*)(Wom + (size_t)k * 108 + q * 4);
            Bs[(q * 4 + 0) * 136 + k] = f2bf(v.x);
            Bs[(q * 4 + 1) * 136 + k] = f2bf(v.y);
            Bs[(q * 4 + 2) * 136 + k] = f2bf(v.z);
            Bs[(q * 4 + 3) * 136 + k] = f2bf(v.w);
        }
    }
    __syncthreads();

    // ---- omb = A @ Wom + bom (cols 0..107, stride 112) ----
    {
        f32x4 acc[7];
#pragma unroll
        for (int j = 0; j < 7; j++) acc[j] = (f32x4){0.f, 0.f, 0.f, 0.f};
#pragma unroll
        for (int kk = 0; kk < 4; kk++) {
            short8 a = *(const short8*)(&As[(w * 16 + lr) * 136 + kk * 32 + lk * 8]);
#pragma unroll
            for (int j = 0; j < 7; j++) {
                short8 b = *(const short8*)(&Bs[(j * 16 + lr) * 136 + kk * 32 + lk * 8]);
                acc[j] = __builtin_amdgcn_mfma_f32_16x16x32_bf16(a, b, acc[j], 0, 0, 0);
            }
        }
        int row0 = block_m + w * 16 + lk * 4;
#pragma unroll
        for (int j = 0; j < 7; j++) {
            int col = j * 16 + lr;
            if (col < 108) {
                float bb = bom[col];
#pragma unroll
                for (int r = 0; r < 4; r++)
                    omb[(size_t)(row0 + r) * 112 + col] = acc[j][r] + bb;
            }
        }
    }
}

// ---------------------------------------------------------------------------
// sample_obn: sample(val, omb) -> As (LDS) -> @Wo -> ybuf (fp32) + BN stats.
// 64-row tile, 256 blocks. Wo converted fp32->bf16 in staging.
// ---------------------------------------------------------------------------
__global__ __launch_bounds__(256) void sample_obn_kernel(
    const unsigned short* __restrict__ val, const float* __restrict__ omb,
    const float* __restrict__ Wo, float* __restrict__ ybuf,
    float* __restrict__ stats_out)
{
    __shared__ unsigned short As[64 * 136];
    __shared__ unsigned short Bs[128 * 136];
    __shared__ float omtile[64 * 108];
    __shared__ float lstat[256];

    const int tid = threadIdx.x;
    const int bid = blockIdx.x;
    const int block_m = bid * 64;
    const int n_img = block_m >> 12;

    lstat[tid] = 0.0f;

    // stage omtile (fp32)
#pragma unroll
    for (int i = 0; i < 7; i++) {
        int id = tid + i * 256;                  // 1728 float4
        if (id < 1728) {
            int r = id / 27, q = id - r * 27;
            *(float4*)(&omtile[r * 108 + q * 4]) =
                *(const float4*)(omb + (size_t)(block_m + r) * 112 + q * 4);
        }
    }
    // Bs <- Wo^T (transpose-convert)
#pragma unroll
    for (int i = 0; i < 16; i++) {
        int id = tid + i * 256;
        int k = id >> 5, n4 = (id & 31) * 4;
        float4 v = *(const float4*)(Wo + (size_t)k * CC + n4);
        Bs[(n4 + 0) * 136 + k] = f2bf(v.x);
        Bs[(n4 + 1) * 136 + k] = f2bf(v.y);
        Bs[(n4 + 2) * 136 + k] = f2bf(v.z);
        Bs[(n4 + 3) * 136 + k] = f2bf(v.w);
    }
    __syncthreads();

    // sample -> As
    {
        const unsigned short* vimg = val + (((size_t)n_img) << 19);
#pragma unroll
        for (int it = 0; it < 4; it++) {
            int lane_id = tid + it * 256;        // 0..1023
            int unit = lane_id >> 2;             // r*4+g
            int l4 = lane_id & 3;
            int r = unit >> 2;
            int g = unit & 3;
            int nl = block_m + r;
            int h  = (nl & 4095) >> 6;
            int wp = nl & 63;
            const float* omr = omtile + r * 108 + g * 27;
            const unsigned short* vb = vimg + g * 32 + l4 * 8;

            float av[8];
#pragma unroll
            for (int q = 0; q < 8; q++) av[q] = 0.f;
#pragma unroll
            for (int k = 0; k < 9; k++) {
                float ox = omr[2 * k];
                float oy = omr[2 * k + 1];
                float mk = omr[18 + k];
                float ly = (float)(h + k / 3 - 1) + oy;
                float lx = (float)(wp + k % 3 - 1) + ox;
                float y0f = floorf(ly), x0f = floorf(lx);
                float wy = ly - y0f, wx = lx - x0f;
                int y0 = (int)y0f, x0 = (int)x0f;
#pragma unroll
                for (int cy = 0; cy < 2; cy++) {
#pragma unroll
                    for (int cx = 0; cx < 2; cx++) {
                        int yi = y0 + cy, xi = x0 + cx;
                        float wgt = (cy ? wy : 1.f - wy) * (cx ? wx : 1.f - wx);
                        bool valid = (yi >= 0) && (yi < HH) && (xi >= 0) && (xi < WW);
                        wgt = mk * (valid ? wgt : 0.f);
                        int yc = min(max(yi, 0), HH - 1);
                        int xc = min(max(xi, 0), WW - 1);
                        uint4 pv = *(const uint4*)(vb + (size_t)(yc * WW + xc) * CC);
                        unsigned pw[4] = {pv.x, pv.y, pv.z, pv.w};
#pragma unroll
                        for (int q = 0; q < 4; q++) {
                            av[2 * q + 0] += bf2f((unsigned short)(pw[q] & 0xffff)) * wgt;
                            av[2 * q + 1] += bf2f((unsigned short)(pw[q] >> 16)) * wgt;
                        }
                    }
                }
            }
            unsigned p0 = (unsigned)f2bf(av[0]) | ((unsigned)f2bf(av[1]) << 16);
            unsigned p1 = (unsigned)f2bf(av[2]) | ((unsigned)f2bf(av[3]) << 16);
            unsigned p2 = (unsigned)f2bf(av[4]) | ((unsigned)f2bf(av[5]) << 16);
            unsigned p3 = (unsigned)f2bf(av[6]) | ((unsigned)f2bf(av[7]) << 16);
            uint4 pk; pk.x = p0; pk.y = p1; pk.z = p2; pk.w = p3;
            *(uint4*)(&As[r * 136 + g * 32 + l4 * 8]) = pk;
        }
    }
    __syncthreads();

    const int w  = tid >> 6;
    const int l  = tid & 63;
    const int lr = l & 15;
    const int lk = l >> 4;

    // ytile = sampled @ Wo ; BN stats
    {
        f32x4 acc[8];
#pragma unroll
        for (int j = 0; j < 8; j++) acc[j] = (f32x4){0.f, 0.f, 0.f, 0.f};
#pragma unroll
        for (int kk = 0; kk < 4; kk++) {
            short8 a = *(const short8*)(&As[(w * 16 + lr) * 136 + kk * 32 + lk * 8]);
#pragma unroll
            for (int j = 0; j < 8; j++) {
                short8 b = *(const short8*)(&Bs[(j * 16 + lr) * 136 + kk * 32 + lk * 8]);
                acc[j] = __builtin_amdgcn_mfma_f32_16x16x32_bf16(a, b, acc[j], 0, 0, 0);
            }
        }
        int row0 = block_m + w * 16 + lk * 4;
#pragma unroll
        for (int j = 0; j < 8; j++) {
            int col = j * 16 + lr;
            float s = 0.f, sq = 0.f;
#pragma unroll
            for (int r = 0; r < 4; r++) {
                float v = acc[j][r];
                ybuf[(size_t)(row0 + r) * CC + col] = v;
                s += v;
                sq += v * v;
            }
            atomicAdd(&lstat[col], s);
            atomicAdd(&lstat[128 + col], sq);
        }
    }
    __syncthreads();
    if (tid < 128) {
        float* sg = stats_out + (bid & 7) * 256;
        atomicAdd(&sg[tid], lstat[tid]);
        atomicAdd(&sg[128 + tid], lstat[128 + tid]);
    }
}

// ---------------------------------------------------------------------------
// final: A = bn(ybuf) + x (NCHW residual), B = Wc; out NCHW fp32.
// ---------------------------------------------------------------------------
__global__ __launch_bounds__(256) void gemm_final_kernel(
    const float* __restrict__ ybuf, const float* __restrict__ x,
    const float* __restrict__ Wc, const float* __restrict__ stats_in,
    const float* __restrict__ gamma, const float* __restrict__ beta,
    float* __restrict__ out)
{
    __shared__ unsigned short As[64 * 136];
    __shared__ unsigned short Bs[128 * 136];
    __shared__ float Xs[64 * 129];
    __shared__ float bnsc[128], bnsh[128];
    float* Tt = (float*)Bs;                      // 128*68*4 = 34816 B, reused post-MFMA

    const int tid = threadIdx.x;
    const int block_m = blockIdx.x * 64;
    const int n_img = block_m >> 12;
    const int hw0 = block_m & 4095;

    if (tid < 128) {
        float s = 0.f, sq = 0.f;
#pragma unroll
        for (int g = 0; g < 8; g++) {
            s  += stats_in[g * 256 + tid];
            sq += stats_in[g * 256 + 128 + tid];
        }
        const float inv = 1.0f / 16384.0f;
        float mean = s * inv;
        float var  = sq * inv - mean * mean;
        float sc   = rsqrtf(var + 1e-5f) * gamma[tid];
        bnsc[tid] = sc;
        bnsh[tid] = beta[tid] - mean * sc;
    }
    // Xs <- x tile (NCHW -> [hw][c])
#pragma unroll
    for (int i = 0; i < 8; i++) {
        int id = tid + i * 256;
        int c = id >> 4, j4 = id & 15;
        float4 v = *(const float4*)(x + (((size_t)(n_img * CC + c)) << 12) + hw0 + j4 * 4);
        Xs[(j4 * 4 + 0) * 129 + c] = v.x;
        Xs[(j4 * 4 + 1) * 129 + c] = v.y;
        Xs[(j4 * 4 + 2) * 129 + c] = v.z;
        Xs[(j4 * 4 + 3) * 129 + c] = v.w;
    }
    // Bs <- Wc (already [o][c] = Bt layout)
#pragma unroll
    for (int i = 0; i < 16; i++) {
        int id = tid + i * 256;
        int r = id >> 5, c4 = (id & 31) * 4;
        float4 v = *(const float4*)(Wc + (size_t)r * CC + c4);
        Bs[r * 136 + c4 + 0] = f2bf(v.x);
        Bs[r * 136 + c4 + 1] = f2bf(v.y);
        Bs[r * 136 + c4 + 2] = f2bf(v.z);
        Bs[r * 136 + c4 + 3] = f2bf(v.w);
    }
    __syncthreads();
    // As <- bf16(bn(ybuf) + Xs)
#pragma unroll
    for (int i = 0; i < 8; i++) {
        int id = tid + i * 256;
        int r = id >> 5, c = (id & 31) * 4;
        float4 yv = *(const float4*)(ybuf + (size_t)(block_m + r) * CC + c);
        As[r * 136 + c + 0] = f2bf(yv.x * bnsc[c + 0] + bnsh[c + 0] + Xs[r * 129 + c + 0]);
        As[r * 136 + c + 1] = f2bf(yv.y * bnsc[c + 1] + bnsh[c + 1] + Xs[r * 129 + c + 1]);
        As[r * 136 + c + 2] = f2bf(yv.z * bnsc[c + 2] + bnsh[c + 2] + Xs[r * 129 + c + 2]);
        As[r * 136 + c + 3] = f2bf(yv.w * bnsc[c + 3] + bnsh[c + 3] + Xs[r * 129 + c + 3]);
    }
    __syncthreads();

    const int w  = tid >> 6;
    const int l  = tid & 63;
    const int lr = l & 15;
    const int lk = l >> 4;
    {
        f32x4 acc[8];
#pragma unroll
        for (int j = 0; j < 8; j++) acc[j] = (f32x4){0.f, 0.f, 0.f, 0.f};
#pragma unroll
        for (int kk = 0; kk < 4; kk++) {
            short8 a = *(const short8*)(&As[(w * 16 + lr) * 136 + kk * 32 + lk * 8]);
#pragma unroll
            for (int j = 0; j < 8; j++) {
                short8 b = *(const short8*)(&Bs[(j * 16 + lr) * 136 + kk * 32 + lk * 8]);
                acc[j] = __builtin_amdgcn_mfma_f32_16x16x32_bf16(a, b, acc[j], 0, 0, 0);
            }
        }
        __syncthreads();          // MFMAs done -> Bs reusable as Tt
        int row0 = w * 16 + lk * 4;
#pragma unroll
        for (int j = 0; j < 8; j++) {
            int col = j * 16 + lr;
#pragma unroll
            for (int r = 0; r < 4; r++)
                Tt[col * 68 + row0 + r] = acc[j][r];
        }
    }
    __syncthreads();
#pragma unroll
    for (int i = 0; i < 8; i++) {
        int id = tid + i * 256;
        int o = id >> 4, j4 = id & 15;
        float4 v = *(const float4*)(&Tt[o * 68 + j4 * 4]);
        *(float4*)(out + (((size_t)(n_img * CC + o)) << 12) + hw0 + j4 * 4) = v;
    }
}

// ---------------------------------------------------------------------------
extern "C" void kernel_launch(void* const* d_in, const int* in_sizes, int n_in,
                              void* d_out, int out_size, void* d_ws, size_t ws_size,
                              hipStream_t stream)
{
    (void)in_sizes; (void)n_in; (void)out_size; (void)ws_size;
    const float* x     = (const float*)d_in[0];
    const float* Wv    = (const float*)d_in[1];
    const float* bv    = (const float*)d_in[2];
    const float* Wom   = (const float*)d_in[3];
    const float* bom   = (const float*)d_in[4];
    const float* Wo    = (const float*)d_in[5];
    const float* gamma = (const float*)d_in[6];
    const float* beta  = (const float*)d_in[7];
    const float* Wc    = (const float*)d_in[8];
    float* out = (float*)d_out;

    char* ws = (char*)d_ws;
    unsigned short* val   = (unsigned short*)ws;   ws += (size_t)NL * CC * 2;   // 4 MB
    float*          omb   = (float*)ws;            ws += (size_t)NL * 112 * 4;  // 7.34 MB
    float*          ybuf  = (float*)ws;            ws += (size_t)NL * CC * 4;   // 8 MB
    float*          stats = (float*)ws;            ws += 4096 * 4;              // 2 sets x 8 groups x 256

    dim3 b256(256);

    // DCN block 1
    gemm_vom_kernel<0><<<256, b256, 0, stream>>>(x, Wv, bv, Wom, bom,
                                                 nullptr, nullptr, nullptr, val, omb, stats);
    sample_obn_kernel<<<256, b256, 0, stream>>>(val, omb, Wo, ybuf, stats);

    // DCN block 2
    gemm_vom_kernel<1><<<256, b256, 0, stream>>>(ybuf, Wv, bv, Wom, bom,
                                                 stats, gamma, beta, val, omb, nullptr);
    sample_obn_kernel<<<256, b256, 0, stream>>>(val, omb, Wo, ybuf, stats + 2048);

    // final
    gemm_final_kernel<<<256, b256, 0, stream>>>(ybuf, x, Wc, stats + 2048, gamma, beta, out);
}